// Round 1
// baseline (666.259 us; speedup 1.0000x reference)
//
#include <hip/hip_runtime.h>
#include <stdint.h>

typedef unsigned int uint;
typedef unsigned short ushort;

#define NNODES 100000
#define NPAD   100096          // NNODES rounded up to 128
#define NEDGES 1600000
#define RCONST 400
#define CAP    64              // fixed per-node edge capacity (Poisson(16): P(deg>63)~8e-20)

// binned CSR build
#define NBKT   196             // ceil(NNODES / 512)
#define NGRP   8               // XCD-locality groups (blockIdx & 7)
#define BCAP   1536            // per-(group,bucket) capacity; mean ~1025, sd ~32 -> 16 sd margin

typedef __attribute__((ext_vector_type(8))) short short8;
typedef __attribute__((ext_vector_type(4))) float f32x4;

__device__ __forceinline__ float bflo(uint u){ union{uint i;float f;}c; c.i=u<<16; return c.f; }
__device__ __forceinline__ float bfhi(uint u){ union{uint i;float f;}c; c.i=u&0xFFFF0000u; return c.f; }
__device__ __forceinline__ ushort f2bf(float f){ union{uint i;float ff;}c; c.ff=f; uint u=c.i;
    return (ushort)((u + 0x7FFFu + ((u>>16)&1u))>>16); }
__device__ __forceinline__ uint pack2(float lo, float hi){
    return (uint)f2bf(lo) | ((uint)f2bf(hi)<<16); }

// ---------------- phase A: bin edges by coarse dst bucket, XCD-locally ----------------
// entry = src(17) | bkt(2)<<17 | (dst&511)<<19  -- 28 bits in a u32.
// Append stream for (group g = blockIdx&7, bucket b = dst>>9) is written only by
// blocks of one XCD (round-robin mapping) -> lines coalesce in that L2, evict once.

__global__ __launch_bounds__(256) void binfill_kernel(const int* __restrict__ edges,
                                                      int* __restrict__ bcnt,
                                                      uint* __restrict__ binned) {
    int e = blockIdx.x * 256 + threadIdx.x;
    int g = blockIdx.x & (NGRP - 1);
    if (e < NEDGES) {
        int src = edges[e * 3];
        int rel = edges[e * 3 + 1];
        int dst = edges[e * 3 + 2];
        int bkt = (rel >= RCONST) + (rel >= 2 * RCONST);
        int b = dst >> 9, off = dst & 511;
        int idx = (g << 8) | b;                 // 256 slots/group for shift-friendly addressing
        int pos = atomicAdd(&bcnt[idx], 1);
        if (pos < BCAP)
            binned[(size_t)idx * BCAP + pos] = (uint)src | ((uint)bkt << 17) | ((uint)off << 19);
    }
}

// ---------------- phase B: per-bucket fine scatter into elist ----------------
// One workgroup owns one bucket (512 dst nodes = 128 KB of elist): all writes for
// that range come from a single XCD -> each dirty line hits HBM once.

__global__ __launch_bounds__(256) void scatter_kernel(const uint* __restrict__ binned,
                                                      const int* __restrict__ bcnt,
                                                      int* __restrict__ cnt,
                                                      int* __restrict__ elist) {
    int b = blockIdx.x;                        // 0..NBKT-1
    int base = b << 9;
    for (int g = 0; g < NGRP; ++g) {
        int idx = (g << 8) | b;
        int n = min(bcnt[idx], BCAP);
        const uint* p = binned + (size_t)idx * BCAP;
        for (int i = threadIdx.x; i < n; i += 256) {
            uint e = p[i];
            int dst = base | (int)(e >> 19);
            int pos = atomicAdd(&cnt[dst], 1);
            if (pos < CAP) elist[(size_t)dst * CAP + pos] = (int)(e & 0x7FFFFu);
        }
    }
}

// ---------------- conversions ----------------

__global__ __launch_bounds__(256) void convx_kernel(const float* __restrict__ x,
                                                    uint* __restrict__ xb) {
    size_t i = (size_t)blockIdx.x * 256 + threadIdx.x;   // pair index
    if (i < (size_t)NNODES * 64) {
        float2 f = *(const float2*)&x[i * 2];
        xb[i] = pack2(f.x, f.y);
    }
}

// Wb[n][k] bf16, k<384: W[k>>7][n][k&127]; k>=384: Ws[n][k-384]
__global__ __launch_bounds__(256) void wconv_kernel(const float* __restrict__ W,
                                                    const float* __restrict__ Ws,
                                                    uint* __restrict__ Wb) {
    int i = blockIdx.x * 256 + threadIdx.x;   // pair index, 128*256
    if (i < 128 * 256) {
        int n = i >> 8, kp = i & 255, k = kp * 2;
        float v0, v1;
        if (k < 384) {
            int r = k >> 7, kk = k & 127;
            const float* p = W + r * 16384 + n * 128 + kk;
            v0 = p[0]; v1 = p[1];
        } else {
            const float* p = Ws + n * 128 + (k - 384);
            v0 = p[0]; v1 = p[1];
        }
        Wb[i] = pack2(v0, v1);
    }
}

// ---------------- gather: one wave per node ----------------
// Reads its <=CAP entries once; per-edge src+bucket pulled to SGPR via
// readlane; one-hot scalar masks feed 6 fmacs; lane 0 also emits cnts.

__global__ __launch_bounds__(256) void gather_kernel(
    const uint* __restrict__ xb,       // [NPAD][64] bf16-pairs
    const int* __restrict__ cnt,       // per-node degree (may exceed CAP in theory)
    const int* __restrict__ elist,     // [NPAD][CAP] entries src|bkt<<17
    uint* __restrict__ Ab,             // [NPAD][192] bf16-pairs
    float4* __restrict__ cnts) {       // per-node (c0,c1,c2,inv)
    int w = threadIdx.x >> 6, lane = threadIdx.x & 63;
    int node = blockIdx.x * 4 + w;     // grid = NNODES/4 exactly
    int deg = min(cnt[node], CAP);
    float inv = 1.0f / fmaxf((float)deg, 1.0f);

    float a0l = 0.f, a0h = 0.f, a1l = 0.f, a1h = 0.f, a2l = 0.f, a2h = 0.f;
    int c0 = 0, c1 = 0, c2 = 0;

    for (int base = 0; base < deg; base += 64) {
        int m = min(64, deg - base);
        int ve = 0;
        if (lane < m) ve = elist[(size_t)node * CAP + base + lane];

        int j = 0;
        for (; j + 4 <= m; j += 4) {
            int e0 = __builtin_amdgcn_readlane(ve, j);
            int e1 = __builtin_amdgcn_readlane(ve, j + 1);
            int e2 = __builtin_amdgcn_readlane(ve, j + 2);
            int e3 = __builtin_amdgcn_readlane(ve, j + 3);
            int s0 = e0 & 0x1FFFF, k0 = e0 >> 17;
            int s1 = e1 & 0x1FFFF, k1 = e1 >> 17;
            int s2 = e2 & 0x1FFFF, k2 = e2 >> 17;
            int s3 = e3 & 0x1FFFF, k3 = e3 >> 17;
            uint u0 = xb[((size_t)s0 << 6) + lane];
            uint u1 = xb[((size_t)s1 << 6) + lane];
            uint u2 = xb[((size_t)s2 << 6) + lane];
            uint u3 = xb[((size_t)s3 << 6) + lane];

            float q00 = (k0 == 0) ? 1.f : 0.f, q01 = (k0 == 1) ? 1.f : 0.f, q02 = (k0 == 2) ? 1.f : 0.f;
            float q10 = (k1 == 0) ? 1.f : 0.f, q11 = (k1 == 1) ? 1.f : 0.f, q12 = (k1 == 2) ? 1.f : 0.f;
            float q20 = (k2 == 0) ? 1.f : 0.f, q21 = (k2 == 1) ? 1.f : 0.f, q22 = (k2 == 2) ? 1.f : 0.f;
            float q30 = (k3 == 0) ? 1.f : 0.f, q31 = (k3 == 1) ? 1.f : 0.f, q32 = (k3 == 2) ? 1.f : 0.f;
            c0 += (k0 == 0) + (k1 == 0) + (k2 == 0) + (k3 == 0);
            c1 += (k0 == 1) + (k1 == 1) + (k2 == 1) + (k3 == 1);
            c2 += (k0 == 2) + (k1 == 2) + (k2 == 2) + (k3 == 2);

            float f0l = bflo(u0), f0h = bfhi(u0);
            float f1l = bflo(u1), f1h = bfhi(u1);
            float f2l = bflo(u2), f2h = bfhi(u2);
            float f3l = bflo(u3), f3h = bfhi(u3);

            a0l = fmaf(q00, f0l, a0l); a1l = fmaf(q01, f0l, a1l); a2l = fmaf(q02, f0l, a2l);
            a0h = fmaf(q00, f0h, a0h); a1h = fmaf(q01, f0h, a1h); a2h = fmaf(q02, f0h, a2h);
            a0l = fmaf(q10, f1l, a0l); a1l = fmaf(q11, f1l, a1l); a2l = fmaf(q12, f1l, a2l);
            a0h = fmaf(q10, f1h, a0h); a1h = fmaf(q11, f1h, a1h); a2h = fmaf(q12, f1h, a2h);
            a0l = fmaf(q20, f2l, a0l); a1l = fmaf(q21, f2l, a1l); a2l = fmaf(q22, f2l, a2l);
            a0h = fmaf(q20, f2h, a0h); a1h = fmaf(q21, f2h, a1h); a2h = fmaf(q22, f2h, a2h);
            a0l = fmaf(q30, f3l, a0l); a1l = fmaf(q31, f3l, a1l); a2l = fmaf(q32, f3l, a2l);
            a0h = fmaf(q30, f3h, a0h); a1h = fmaf(q31, f3h, a1h); a2h = fmaf(q32, f3h, a2h);
        }
        for (; j < m; ++j) {
            int ee = __builtin_amdgcn_readlane(ve, j);
            int s = ee & 0x1FFFF, k = ee >> 17;
            uint u = xb[((size_t)s << 6) + lane];
            float q0 = (k == 0) ? 1.f : 0.f;
            float q1 = (k == 1) ? 1.f : 0.f;
            float q2 = (k == 2) ? 1.f : 0.f;
            c0 += (k == 0); c1 += (k == 1); c2 += (k == 2);
            float fl = bflo(u), fh = bfhi(u);
            a0l = fmaf(q0, fl, a0l); a1l = fmaf(q1, fl, a1l); a2l = fmaf(q2, fl, a2l);
            a0h = fmaf(q0, fh, a0h); a1h = fmaf(q1, fh, a1h); a2h = fmaf(q2, fh, a2h);
        }
    }

    size_t ab = (size_t)node * 192 + lane;
    Ab[ab]       = pack2(a0l * inv, a0h * inv);
    Ab[ab + 64]  = pack2(a1l * inv, a1h * inv);
    Ab[ab + 128] = pack2(a2l * inv, a2h * inv);
    if (lane == 0) {
        float4 v; v.x = (float)c0; v.y = (float)c1; v.z = (float)c2; v.w = inv;
        cnts[node] = v;
    }
}

// ---------------- MFMA GEMM + fused epilogue ----------------

template<bool OUT_BF16>
__global__ __launch_bounds__(256, 2) void gemm_kernel(
    const ushort* __restrict__ Ab,     // [NPAD][384]
    const ushort* __restrict__ xb,     // [NPAD][128]
    const ushort* __restrict__ Wb,     // [128][512]
    const float* __restrict__ bia,     // [3][128]
    const float* __restrict__ bs,
    const float* __restrict__ g,
    const float* __restrict__ be,
    const float4* __restrict__ cnts,   // [NPAD] (c0,c1,c2,inv)
    void* __restrict__ out) {
    __shared__ char smem[128 * 136 * 2 * 2];   // A-stage + B-stage, reused as v-tile
    __shared__ float sMean[128], sRstd[128];
    ushort (*lA)[136] = (ushort(*)[136])smem;
    ushort (*lB)[136] = (ushort(*)[136])(smem + 128 * 136 * 2);
    float  (*vt)[132] = (float(*)[132])smem;

    int tid = threadIdx.x;
    int w = tid >> 6, lane = tid & 63;
    int wm = w >> 1, wn = w & 1;
    int quad = lane >> 4, l15 = lane & 15;
    int node0 = blockIdx.x * 128;

    f32x4 accm[4][4], accq[4][4];
    f32x4 zero = {0.f, 0.f, 0.f, 0.f};
    #pragma unroll
    for (int i = 0; i < 4; ++i)
        #pragma unroll
        for (int j = 0; j < 4; ++j) { accm[i][j] = zero; accq[i][j] = zero; }

    for (int kc = 0; kc < 4; ++kc) {
        const ushort* srcA; int strA;
        if (kc < 3) { srcA = Ab + (size_t)node0 * 384 + kc * 128; strA = 384; }
        else        { srcA = xb + (size_t)node0 * 128;            strA = 128; }
        const ushort* srcB = Wb + kc * 128;
        __syncthreads();
        #pragma unroll
        for (int i = 0; i < 8; ++i) {
            int li = i * 256 + tid;            // 0..2047
            int row = li >> 4, cs = li & 15;
            *(uint4*)&lA[row][cs * 8] = *(const uint4*)(srcA + (size_t)row * strA + cs * 8);
            *(uint4*)&lB[row][cs * 8] = *(const uint4*)(srcB + (size_t)row * 512  + cs * 8);
        }
        __syncthreads();
        #pragma unroll
        for (int ks = 0; ks < 4; ++ks) {
            short8 aF[4], bF[4];
            #pragma unroll
            for (int mt = 0; mt < 4; ++mt)
                aF[mt] = *(const short8*)&lA[wm * 64 + mt * 16 + l15][ks * 32 + quad * 8];
            #pragma unroll
            for (int nt = 0; nt < 4; ++nt)
                bF[nt] = *(const short8*)&lB[wn * 64 + nt * 16 + l15][ks * 32 + quad * 8];
            if (kc < 3) {
                #pragma unroll
                for (int mt = 0; mt < 4; ++mt)
                    #pragma unroll
                    for (int nt = 0; nt < 4; ++nt)
                        accm[mt][nt] = __builtin_amdgcn_mfma_f32_16x16x32_bf16(
                            aF[mt], bF[nt], accm[mt][nt], 0, 0, 0);
            } else {
                #pragma unroll
                for (int mt = 0; mt < 4; ++mt)
                    #pragma unroll
                    for (int nt = 0; nt < 4; ++nt)
                        accq[mt][nt] = __builtin_amdgcn_mfma_f32_16x16x32_bf16(
                            aF[mt], bF[nt], accq[mt][nt], 0, 0, 0);
            }
        }
    }

    __syncthreads();   // all fragment reads done; smem becomes v-tile
    #pragma unroll
    for (int mt = 0; mt < 4; ++mt) {
        #pragma unroll
        for (int r = 0; r < 4; ++r) {
            int ml = wm * 64 + mt * 16 + quad * 4 + r;
            float4 c4 = cnts[node0 + ml];
            #pragma unroll
            for (int nt = 0; nt < 4; ++nt) {
                int nl = wn * 64 + nt * 16 + l15;
                float bd = (c4.x * bia[nl] + c4.y * bia[128 + nl] + c4.z * bia[256 + nl]) * c4.w;
                float mval = accm[mt][nt][r] + bd;
                float v = fmaxf(mval, 0.f) + accq[mt][nt][r] + bs[nl];
                vt[ml][nl] = v;
            }
        }
    }
    __syncthreads();
    if (tid < 128) {
        float s1 = 0.f, s2 = 0.f;
        const float* row = vt[tid];
        #pragma unroll 8
        for (int c = 0; c < 128; c += 4) {
            float4 a = *(const float4*)&row[c];
            s1 += (a.x + a.y) + (a.z + a.w);
            s2 += (a.x * a.x + a.y * a.y) + (a.z * a.z + a.w * a.w);
        }
        float mean = s1 * (1.f / 128.f);
        float var = s2 * (1.f / 128.f) - mean * mean;
        sMean[tid] = mean;
        sRstd[tid] = rsqrtf(var + 1e-5f);
    }
    __syncthreads();
    if (OUT_BF16) {
        uint* o = (uint*)out;
        for (int idx = tid; idx < 128 * 64; idx += 256) {
            int row = idx >> 6, cp = idx & 63;
            int node = node0 + row;
            if (node < NNODES) {
                float mn = sMean[row], rs = sRstd[row];
                int c0 = cp * 2;
                float v0 = (vt[row][c0] - mn) * rs * g[c0] + be[c0];
                float v1 = (vt[row][c0 + 1] - mn) * rs * g[c0 + 1] + be[c0 + 1];
                o[(size_t)node * 64 + cp] = pack2(v0, v1);
            }
        }
    } else {
        float* o = (float*)out;
        for (int idx = tid; idx < 128 * 128; idx += 256) {
            int row = idx >> 7, col = idx & 127;
            int node = node0 + row;
            if (node < NNODES)
                o[(size_t)node * 128 + col] =
                    (vt[row][col] - sMean[row]) * sRstd[row] * g[col] + be[col];
        }
    }
}

// ---------------- launch ----------------

extern "C" void kernel_launch(void* const* d_in, const int* in_sizes, int n_in,
                              void* d_out, int out_size, void* d_ws, size_t ws_size,
                              hipStream_t stream) {
    (void)in_sizes; (void)n_in; (void)out_size; (void)ws_size;

    const int*   edges = (const int*)d_in[0];
    const float* xemb  = (const float*)d_in[1];
    const float* W1  = (const float*)d_in[2];
    const float* b1  = (const float*)d_in[3];
    const float* Ws1 = (const float*)d_in[4];
    const float* bs1 = (const float*)d_in[5];
    const float* g1  = (const float*)d_in[6];
    const float* be1 = (const float*)d_in[7];
    const float* W2  = (const float*)d_in[8];
    const float* b2  = (const float*)d_in[9];
    const float* Ws2 = (const float*)d_in[10];
    const float* bs2 = (const float*)d_in[11];
    const float* g2  = (const float*)d_in[12];
    const float* be2 = (const float*)d_in[13];

    char* ws = (char*)d_ws;
    auto take = [&](size_t bytes) {
        char* p = ws;
        ws += (bytes + 255) & ~(size_t)255;
        return p;
    };
    int*    cnt    = (int*)take((size_t)NPAD * 4);
    int*    elist  = (int*)take((size_t)NPAD * CAP * 4);
    float4* cnts   = (float4*)take((size_t)NPAD * 16);
    uint*   xb0    = (uint*)take((size_t)NPAD * 128 * 2);
    uint*   xb1    = (uint*)take((size_t)NPAD * 128 * 2);
    uint*   Ab     = (uint*)take((size_t)NPAD * 384 * 2);
    uint*   Wb1    = (uint*)take((size_t)128 * 512 * 2);
    uint*   Wb2    = (uint*)take((size_t)128 * 512 * 2);
    int*    bcnt   = (int*)take((size_t)NGRP * 256 * 4);
    uint*   binned = (uint*)take((size_t)NGRP * 256 * BCAP * 4);

    hipMemsetAsync(cnt, 0, (size_t)NPAD * 4, stream);
    hipMemsetAsync(bcnt, 0, (size_t)NGRP * 256 * 4, stream);

    binfill_kernel<<<(NEDGES + 255) / 256, 256, 0, stream>>>(edges, bcnt, binned);
    scatter_kernel<<<NBKT, 256, 0, stream>>>(binned, bcnt, cnt, elist);

    convx_kernel<<<(NNODES * 64) / 256, 256, 0, stream>>>(xemb, xb0);
    wconv_kernel<<<128, 256, 0, stream>>>(W1, Ws1, Wb1);
    wconv_kernel<<<128, 256, 0, stream>>>(W2, Ws2, Wb2);

    gather_kernel<<<NNODES / 4, 256, 0, stream>>>(xb0, cnt, elist, Ab, cnts);
    gemm_kernel<true><<<(NNODES + 127) / 128, 256, 0, stream>>>(
        (const ushort*)Ab, (const ushort*)xb0, (const ushort*)Wb1,
        b1, bs1, g1, be1, cnts, xb1);

    gather_kernel<<<NNODES / 4, 256, 0, stream>>>(xb1, cnt, elist, Ab, cnts);
    gemm_kernel<false><<<(NNODES + 127) / 128, 256, 0, stream>>>(
        (const ushort*)Ab, (const ushort*)xb1, (const ushort*)Wb2,
        b2, bs2, g2, be2, cnts, d_out);
}

// Round 2
// 453.109 us; speedup vs baseline: 1.4704x; 1.4704x over previous
//
#include <hip/hip_runtime.h>
#include <stdint.h>

typedef unsigned int uint;
typedef unsigned short ushort;

#define NNODES 100000
#define NPAD   100096          // NNODES rounded up to 128
#define NEDGES 1600000
#define RCONST 400
#define CAP    64              // fixed per-node edge capacity (Poisson(16): P(deg>63)~8e-20)

// atomic-free binned CSR build
#define NBKT   196             // ceil(NPAD / 512)
#define NBLK_A 512             // binfill blocks
#define EPB    3125            // NEDGES / NBLK_A, exact
#define RUNCAP 64              // per-(block,bucket) slot capacity; mean 16, P(>64)~2e-18

typedef __attribute__((ext_vector_type(8))) short short8;
typedef __attribute__((ext_vector_type(4))) float f32x4;

__device__ __forceinline__ float bflo(uint u){ union{uint i;float f;}c; c.i=u<<16; return c.f; }
__device__ __forceinline__ float bfhi(uint u){ union{uint i;float f;}c; c.i=u&0xFFFF0000u; return c.f; }
__device__ __forceinline__ ushort f2bf(float f){ union{uint i;float ff;}c; c.ff=f; uint u=c.i;
    return (ushort)((u + 0x7FFFu + ((u>>16)&1u))>>16); }
__device__ __forceinline__ uint pack2(float lo, float hi){
    return (uint)f2bf(lo) | ((uint)f2bf(hi)<<16); }

// ---------------- phase A: bin edges by coarse dst bucket, atomic-free ----------------
// entry = src(17) | bkt(2)<<17 | (dst&511)<<19.
// Slot for (bucket b, block blk, pos p) is DETERMINISTIC: binned[(b*NBLK_A+blk)*RUNCAP+p].
// Positions come from per-block LDS counters -> zero global atomics. Runs are 256B
// line-aligned so no two blocks ever dirty the same line.

__global__ __launch_bounds__(256) void binfill_kernel(const int* __restrict__ edges,
                                                      int* __restrict__ runcnt,   // [NBLK_A][NBKT]
                                                      uint* __restrict__ binned) { // [NBKT][NBLK_A][RUNCAP]
    __shared__ int pos[NBKT];
    int blk = blockIdx.x, tid = threadIdx.x;
    for (int i = tid; i < NBKT; i += 256) pos[i] = 0;
    __syncthreads();
    int start = blk * EPB;
    for (int i = tid; i < EPB; i += 256) {
        int e = start + i;
        int src = edges[e * 3];
        int rel = edges[e * 3 + 1];
        int dst = edges[e * 3 + 2];
        int bkt = (rel >= RCONST) + (rel >= 2 * RCONST);
        int b = dst >> 9, off = dst & 511;
        int p = atomicAdd(&pos[b], 1);         // LDS atomic
        if (p < RUNCAP)
            binned[((size_t)b * NBLK_A + blk) * RUNCAP + p] =
                (uint)src | ((uint)bkt << 17) | ((uint)off << 19);
    }
    __syncthreads();
    for (int i = tid; i < NBKT; i += 256)
        runcnt[blk * NBKT + i] = min(pos[i], RUNCAP);
}

// ---------------- phase B: per-bucket fine scatter into elist, LDS positions ----------------
// One workgroup owns one bucket (512 dst nodes = 128 KB of elist): per-node slot
// positions live in LDS (no global atomics), and all elist writes for that range
// come from a single XCD -> each dirty line hits HBM once. Also emits cnt[] as
// plain stores, removing the need for any memset.

__global__ __launch_bounds__(256) void scatter_kernel(const uint* __restrict__ binned,
                                                      const int* __restrict__ runcnt,
                                                      int* __restrict__ cnt,
                                                      int* __restrict__ elist) {
    __shared__ int c512[512];
    int b = blockIdx.x, tid = threadIdx.x;
    int base = b << 9;
    for (int i = tid; i < 512; i += 256) c512[i] = 0;
    __syncthreads();
    #pragma unroll
    for (int rr = 0; rr < 2; ++rr) {
        int r = tid * 2 + rr;                  // each thread drains 2 runs
        int n = runcnt[r * NBKT + b];
        const uint* p = binned + ((size_t)b * NBLK_A + r) * RUNCAP;
        for (int i = 0; i < n; ++i) {
            uint e = p[i];
            int off = (int)(e >> 19);
            int q = atomicAdd(&c512[off], 1);  // LDS atomic
            if (q < CAP) elist[(size_t)(base + off) * CAP + q] = (int)(e & 0x7FFFFu);
        }
    }
    __syncthreads();
    for (int i = tid; i < 512; i += 256) {
        int node = base + i;
        if (node < NPAD) cnt[node] = min(c512[i], CAP);
    }
}

// ---------------- conversions ----------------

__global__ __launch_bounds__(256) void convx_kernel(const float* __restrict__ x,
                                                    uint* __restrict__ xb) {
    size_t i = (size_t)blockIdx.x * 256 + threadIdx.x;   // pair index
    if (i < (size_t)NNODES * 64) {
        float2 f = *(const float2*)&x[i * 2];
        xb[i] = pack2(f.x, f.y);
    }
}

// Wb[n][k] bf16, k<384: W[k>>7][n][k&127]; k>=384: Ws[n][k-384]
__global__ __launch_bounds__(256) void wconv_kernel(const float* __restrict__ W,
                                                    const float* __restrict__ Ws,
                                                    uint* __restrict__ Wb) {
    int i = blockIdx.x * 256 + threadIdx.x;   // pair index, 128*256
    if (i < 128 * 256) {
        int n = i >> 8, kp = i & 255, k = kp * 2;
        float v0, v1;
        if (k < 384) {
            int r = k >> 7, kk = k & 127;
            const float* p = W + r * 16384 + n * 128 + kk;
            v0 = p[0]; v1 = p[1];
        } else {
            const float* p = Ws + n * 128 + (k - 384);
            v0 = p[0]; v1 = p[1];
        }
        Wb[i] = pack2(v0, v1);
    }
}

// ---------------- gather: one wave per node ----------------
// Reads its <=CAP entries once; per-edge src+bucket pulled to SGPR via
// readlane; one-hot scalar masks feed 6 fmacs; lane 0 also emits cnts.

__global__ __launch_bounds__(256) void gather_kernel(
    const uint* __restrict__ xb,       // [NPAD][64] bf16-pairs
    const int* __restrict__ cnt,       // per-node degree (clamped to CAP)
    const int* __restrict__ elist,     // [NPAD][CAP] entries src|bkt<<17
    uint* __restrict__ Ab,             // [NPAD][192] bf16-pairs
    float4* __restrict__ cnts) {       // per-node (c0,c1,c2,inv)
    int w = threadIdx.x >> 6, lane = threadIdx.x & 63;
    int node = blockIdx.x * 4 + w;     // grid = NNODES/4 exactly
    int deg = min(cnt[node], CAP);
    float inv = 1.0f / fmaxf((float)deg, 1.0f);

    float a0l = 0.f, a0h = 0.f, a1l = 0.f, a1h = 0.f, a2l = 0.f, a2h = 0.f;
    int c0 = 0, c1 = 0, c2 = 0;

    for (int base = 0; base < deg; base += 64) {
        int m = min(64, deg - base);
        int ve = 0;
        if (lane < m) ve = elist[(size_t)node * CAP + base + lane];

        int j = 0;
        for (; j + 4 <= m; j += 4) {
            int e0 = __builtin_amdgcn_readlane(ve, j);
            int e1 = __builtin_amdgcn_readlane(ve, j + 1);
            int e2 = __builtin_amdgcn_readlane(ve, j + 2);
            int e3 = __builtin_amdgcn_readlane(ve, j + 3);
            int s0 = e0 & 0x1FFFF, k0 = e0 >> 17;
            int s1 = e1 & 0x1FFFF, k1 = e1 >> 17;
            int s2 = e2 & 0x1FFFF, k2 = e2 >> 17;
            int s3 = e3 & 0x1FFFF, k3 = e3 >> 17;
            uint u0 = xb[((size_t)s0 << 6) + lane];
            uint u1 = xb[((size_t)s1 << 6) + lane];
            uint u2 = xb[((size_t)s2 << 6) + lane];
            uint u3 = xb[((size_t)s3 << 6) + lane];

            float q00 = (k0 == 0) ? 1.f : 0.f, q01 = (k0 == 1) ? 1.f : 0.f, q02 = (k0 == 2) ? 1.f : 0.f;
            float q10 = (k1 == 0) ? 1.f : 0.f, q11 = (k1 == 1) ? 1.f : 0.f, q12 = (k1 == 2) ? 1.f : 0.f;
            float q20 = (k2 == 0) ? 1.f : 0.f, q21 = (k2 == 1) ? 1.f : 0.f, q22 = (k2 == 2) ? 1.f : 0.f;
            float q30 = (k3 == 0) ? 1.f : 0.f, q31 = (k3 == 1) ? 1.f : 0.f, q32 = (k3 == 2) ? 1.f : 0.f;
            c0 += (k0 == 0) + (k1 == 0) + (k2 == 0) + (k3 == 0);
            c1 += (k0 == 1) + (k1 == 1) + (k2 == 1) + (k3 == 1);
            c2 += (k0 == 2) + (k1 == 2) + (k2 == 2) + (k3 == 2);

            float f0l = bflo(u0), f0h = bfhi(u0);
            float f1l = bflo(u1), f1h = bfhi(u1);
            float f2l = bflo(u2), f2h = bfhi(u2);
            float f3l = bflo(u3), f3h = bfhi(u3);

            a0l = fmaf(q00, f0l, a0l); a1l = fmaf(q01, f0l, a1l); a2l = fmaf(q02, f0l, a2l);
            a0h = fmaf(q00, f0h, a0h); a1h = fmaf(q01, f0h, a1h); a2h = fmaf(q02, f0h, a2h);
            a0l = fmaf(q10, f1l, a0l); a1l = fmaf(q11, f1l, a1l); a2l = fmaf(q12, f1l, a2l);
            a0h = fmaf(q10, f1h, a0h); a1h = fmaf(q11, f1h, a1h); a2h = fmaf(q12, f1h, a2h);
            a0l = fmaf(q20, f2l, a0l); a1l = fmaf(q21, f2l, a1l); a2l = fmaf(q22, f2l, a2l);
            a0h = fmaf(q20, f2h, a0h); a1h = fmaf(q21, f2h, a1h); a2h = fmaf(q22, f2h, a2h);
            a0l = fmaf(q30, f3l, a0l); a1l = fmaf(q31, f3l, a1l); a2l = fmaf(q32, f3l, a2l);
            a0h = fmaf(q30, f3h, a0h); a1h = fmaf(q31, f3h, a1h); a2h = fmaf(q32, f3h, a2h);
        }
        for (; j < m; ++j) {
            int ee = __builtin_amdgcn_readlane(ve, j);
            int s = ee & 0x1FFFF, k = ee >> 17;
            uint u = xb[((size_t)s << 6) + lane];
            float q0 = (k == 0) ? 1.f : 0.f;
            float q1 = (k == 1) ? 1.f : 0.f;
            float q2 = (k == 2) ? 1.f : 0.f;
            c0 += (k == 0); c1 += (k == 1); c2 += (k == 2);
            float fl = bflo(u), fh = bfhi(u);
            a0l = fmaf(q0, fl, a0l); a1l = fmaf(q1, fl, a1l); a2l = fmaf(q2, fl, a2l);
            a0h = fmaf(q0, fh, a0h); a1h = fmaf(q1, fh, a1h); a2h = fmaf(q2, fh, a2h);
        }
    }

    size_t ab = (size_t)node * 192 + lane;
    Ab[ab]       = pack2(a0l * inv, a0h * inv);
    Ab[ab + 64]  = pack2(a1l * inv, a1h * inv);
    Ab[ab + 128] = pack2(a2l * inv, a2h * inv);
    if (lane == 0) {
        float4 v; v.x = (float)c0; v.y = (float)c1; v.z = (float)c2; v.w = inv;
        cnts[node] = v;
    }
}

// ---------------- MFMA GEMM + fused epilogue ----------------

template<bool OUT_BF16>
__global__ __launch_bounds__(256, 2) void gemm_kernel(
    const ushort* __restrict__ Ab,     // [NPAD][384]
    const ushort* __restrict__ xb,     // [NPAD][128]
    const ushort* __restrict__ Wb,     // [128][512]
    const float* __restrict__ bia,     // [3][128]
    const float* __restrict__ bs,
    const float* __restrict__ g,
    const float* __restrict__ be,
    const float4* __restrict__ cnts,   // [NPAD] (c0,c1,c2,inv)
    void* __restrict__ out) {
    __shared__ char smem[128 * 136 * 2 * 2];   // A-stage + B-stage, reused as v-tile
    __shared__ float sMean[128], sRstd[128];
    ushort (*lA)[136] = (ushort(*)[136])smem;
    ushort (*lB)[136] = (ushort(*)[136])(smem + 128 * 136 * 2);
    float  (*vt)[132] = (float(*)[132])smem;

    int tid = threadIdx.x;
    int w = tid >> 6, lane = tid & 63;
    int wm = w >> 1, wn = w & 1;
    int quad = lane >> 4, l15 = lane & 15;
    int node0 = blockIdx.x * 128;

    f32x4 accm[4][4], accq[4][4];
    f32x4 zero = {0.f, 0.f, 0.f, 0.f};
    #pragma unroll
    for (int i = 0; i < 4; ++i)
        #pragma unroll
        for (int j = 0; j < 4; ++j) { accm[i][j] = zero; accq[i][j] = zero; }

    for (int kc = 0; kc < 4; ++kc) {
        const ushort* srcA; int strA;
        if (kc < 3) { srcA = Ab + (size_t)node0 * 384 + kc * 128; strA = 384; }
        else        { srcA = xb + (size_t)node0 * 128;            strA = 128; }
        const ushort* srcB = Wb + kc * 128;
        __syncthreads();
        #pragma unroll
        for (int i = 0; i < 8; ++i) {
            int li = i * 256 + tid;            // 0..2047
            int row = li >> 4, cs = li & 15;
            *(uint4*)&lA[row][cs * 8] = *(const uint4*)(srcA + (size_t)row * strA + cs * 8);
            *(uint4*)&lB[row][cs * 8] = *(const uint4*)(srcB + (size_t)row * 512  + cs * 8);
        }
        __syncthreads();
        #pragma unroll
        for (int ks = 0; ks < 4; ++ks) {
            short8 aF[4], bF[4];
            #pragma unroll
            for (int mt = 0; mt < 4; ++mt)
                aF[mt] = *(const short8*)&lA[wm * 64 + mt * 16 + l15][ks * 32 + quad * 8];
            #pragma unroll
            for (int nt = 0; nt < 4; ++nt)
                bF[nt] = *(const short8*)&lB[wn * 64 + nt * 16 + l15][ks * 32 + quad * 8];
            if (kc < 3) {
                #pragma unroll
                for (int mt = 0; mt < 4; ++mt)
                    #pragma unroll
                    for (int nt = 0; nt < 4; ++nt)
                        accm[mt][nt] = __builtin_amdgcn_mfma_f32_16x16x32_bf16(
                            aF[mt], bF[nt], accm[mt][nt], 0, 0, 0);
            } else {
                #pragma unroll
                for (int mt = 0; mt < 4; ++mt)
                    #pragma unroll
                    for (int nt = 0; nt < 4; ++nt)
                        accq[mt][nt] = __builtin_amdgcn_mfma_f32_16x16x32_bf16(
                            aF[mt], bF[nt], accq[mt][nt], 0, 0, 0);
            }
        }
    }

    __syncthreads();   // all fragment reads done; smem becomes v-tile
    #pragma unroll
    for (int mt = 0; mt < 4; ++mt) {
        #pragma unroll
        for (int r = 0; r < 4; ++r) {
            int ml = wm * 64 + mt * 16 + quad * 4 + r;
            float4 c4 = cnts[node0 + ml];
            #pragma unroll
            for (int nt = 0; nt < 4; ++nt) {
                int nl = wn * 64 + nt * 16 + l15;
                float bd = (c4.x * bia[nl] + c4.y * bia[128 + nl] + c4.z * bia[256 + nl]) * c4.w;
                float mval = accm[mt][nt][r] + bd;
                float v = fmaxf(mval, 0.f) + accq[mt][nt][r] + bs[nl];
                vt[ml][nl] = v;
            }
        }
    }
    __syncthreads();
    if (tid < 128) {
        float s1 = 0.f, s2 = 0.f;
        const float* row = vt[tid];
        #pragma unroll 8
        for (int c = 0; c < 128; c += 4) {
            float4 a = *(const float4*)&row[c];
            s1 += (a.x + a.y) + (a.z + a.w);
            s2 += (a.x * a.x + a.y * a.y) + (a.z * a.z + a.w * a.w);
        }
        float mean = s1 * (1.f / 128.f);
        float var = s2 * (1.f / 128.f) - mean * mean;
        sMean[tid] = mean;
        sRstd[tid] = rsqrtf(var + 1e-5f);
    }
    __syncthreads();
    if (OUT_BF16) {
        uint* o = (uint*)out;
        for (int idx = tid; idx < 128 * 64; idx += 256) {
            int row = idx >> 6, cp = idx & 63;
            int node = node0 + row;
            if (node < NNODES) {
                float mn = sMean[row], rs = sRstd[row];
                int c0 = cp * 2;
                float v0 = (vt[row][c0] - mn) * rs * g[c0] + be[c0];
                float v1 = (vt[row][c0 + 1] - mn) * rs * g[c0 + 1] + be[c0 + 1];
                o[(size_t)node * 64 + cp] = pack2(v0, v1);
            }
        }
    } else {
        float* o = (float*)out;
        for (int idx = tid; idx < 128 * 128; idx += 256) {
            int row = idx >> 7, col = idx & 127;
            int node = node0 + row;
            if (node < NNODES)
                o[(size_t)node * 128 + col] =
                    (vt[row][col] - sMean[row]) * sRstd[row] * g[col] + be[col];
        }
    }
}

// ---------------- launch ----------------

extern "C" void kernel_launch(void* const* d_in, const int* in_sizes, int n_in,
                              void* d_out, int out_size, void* d_ws, size_t ws_size,
                              hipStream_t stream) {
    (void)in_sizes; (void)n_in; (void)out_size; (void)ws_size;

    const int*   edges = (const int*)d_in[0];
    const float* xemb  = (const float*)d_in[1];
    const float* W1  = (const float*)d_in[2];
    const float* b1  = (const float*)d_in[3];
    const float* Ws1 = (const float*)d_in[4];
    const float* bs1 = (const float*)d_in[5];
    const float* g1  = (const float*)d_in[6];
    const float* be1 = (const float*)d_in[7];
    const float* W2  = (const float*)d_in[8];
    const float* b2  = (const float*)d_in[9];
    const float* Ws2 = (const float*)d_in[10];
    const float* bs2 = (const float*)d_in[11];
    const float* g2  = (const float*)d_in[12];
    const float* be2 = (const float*)d_in[13];

    char* ws = (char*)d_ws;
    auto take = [&](size_t bytes) {
        char* p = ws;
        ws += (bytes + 255) & ~(size_t)255;
        return p;
    };
    int*    cnt    = (int*)take((size_t)NPAD * 4);
    int*    elist  = (int*)take((size_t)NPAD * CAP * 4);
    float4* cnts   = (float4*)take((size_t)NPAD * 16);
    uint*   xb0    = (uint*)take((size_t)NPAD * 128 * 2);
    uint*   xb1    = (uint*)take((size_t)NPAD * 128 * 2);
    uint*   Ab     = (uint*)take((size_t)NPAD * 384 * 2);
    uint*   Wb1    = (uint*)take((size_t)128 * 512 * 2);
    uint*   Wb2    = (uint*)take((size_t)128 * 512 * 2);
    int*    runcnt = (int*)take((size_t)NBLK_A * NBKT * 4);
    uint*   binned = (uint*)take((size_t)NBKT * NBLK_A * RUNCAP * 4);

    binfill_kernel<<<NBLK_A, 256, 0, stream>>>(edges, runcnt, binned);
    scatter_kernel<<<NBKT, 256, 0, stream>>>(binned, runcnt, cnt, elist);

    convx_kernel<<<(NNODES * 64) / 256, 256, 0, stream>>>(xemb, xb0);
    wconv_kernel<<<128, 256, 0, stream>>>(W1, Ws1, Wb1);
    wconv_kernel<<<128, 256, 0, stream>>>(W2, Ws2, Wb2);

    gather_kernel<<<NNODES / 4, 256, 0, stream>>>(xb0, cnt, elist, Ab, cnts);
    gemm_kernel<true><<<(NNODES + 127) / 128, 256, 0, stream>>>(
        (const ushort*)Ab, (const ushort*)xb0, (const ushort*)Wb1,
        b1, bs1, g1, be1, cnts, xb1);

    gather_kernel<<<NNODES / 4, 256, 0, stream>>>(xb1, cnt, elist, Ab, cnts);
    gemm_kernel<false><<<(NNODES + 127) / 128, 256, 0, stream>>>(
        (const ushort*)Ab, (const ushort*)xb1, (const ushort*)Wb2,
        b2, bs2, g2, be2, cnts, d_out);
}